// Round 7
// baseline (617.822 us; speedup 1.0000x reference)
//
#include <hip/hip_runtime.h>
#include <hip/hip_fp16.h>
#include <math.h>

// ---------------------------------------------------------------------------
// GCN 3-layer forward, round 17: direct CSR build (no slab, no bucket sort).
// out[i] = dinv[i] * ( sum_{e:dst=i} Hs[src] + Hs[i] ) + b,  Hs = (X@W)*dinv.
// Round-17 delta vs round-11/15:
//  - CSR: deg-count (global atomics, L2-hot 400KB) -> rows kernel (brute
//    per-chunk prefix over L2-cached deg + 256-wide local scan) -> scatter
//    (srcS[cursor[dst]++] = src). Deletes: 12.8MB slab write, 12.8MB slab
//    read, 6.4M contended LDS atomics, LDS sort + binary search.
//  - lin1/lin2: 2 node-tiles per WG (782 WGs; 391 was ~1.5 waves/SIMD).
//  - agg64 / agg6_lsm: byte-identical to round-11 (proven 55.8us).
// ---------------------------------------------------------------------------

#define WS_ALIGN(x) (((x) + 255) & ~(size_t)255)
#define EPT 8
#define CNT_THR 512
#define CNT_CHUNK (CNT_THR * EPT)   // 4096 edges per WG

typedef _Float16 half8 __attribute__((ext_vector_type(8)));
typedef float floatx4 __attribute__((ext_vector_type(4)));

// ---------------- CSR 1: in-degree histogram ----------------
__global__ __launch_bounds__(CNT_THR) void count_kernel(
    const int* __restrict__ dst, int* __restrict__ deg, int E) {
    const int base = blockIdx.x * CNT_CHUNK + threadIdx.x * EPT;
    #pragma unroll
    for (int k = 0; k < EPT; ++k) {
        int e = base + k;
        if (e < E) atomicAdd(&deg[dst[e]], 1);   // contiguous int4 loads
    }
}

// ---------------- CSR 2: rows/cursor/dinv via brute prefix + local scan ----------------
// WG b handles nodes [b*256, b*256+256). Prefix base = sum(deg[0..b*256)),
// computed by brute force from L2-cached deg (78MB aggregate L2 reads ~ 2us).
__global__ __launch_bounds__(256) void rows_kernel(
    const int* __restrict__ deg, int2* __restrict__ rows,
    int* __restrict__ cursor, float* __restrict__ dinv, int n) {
    __shared__ int red[256];
    __shared__ int sc[256];
    const int tid = threadIdx.x;
    const int limit = blockIdx.x * 256;      // elements before this chunk
    // brute partial sum over deg[0..limit), int4-vectorized (limit % 256 == 0)
    int psum = 0;
    for (int i = tid * 4; i < limit; i += 256 * 4) {
        const int4 v = *(const int4*)&deg[i];
        psum += v.x + v.y + v.z + v.w;
    }
    red[tid] = psum;
    __syncthreads();
    for (int off = 128; off > 0; off >>= 1) {
        if (tid < off) red[tid] += red[tid + off];
        __syncthreads();
    }
    const int base = red[0];
    // local inclusive scan of this chunk's degrees
    const int node = limit + tid;
    const int d = (node < n) ? deg[node] : 0;
    sc[tid] = d;
    __syncthreads();
    for (int off = 1; off < 256; off <<= 1) {
        int v = (tid >= off) ? sc[tid - off] : 0;
        __syncthreads();
        sc[tid] += v;
        __syncthreads();
    }
    if (node < n) {
        const int start = base + sc[tid] - d;
        rows[node] = make_int2(start, start + d);
        cursor[node] = start;
        dinv[node] = rsqrtf((float)(d + 1));   // +1 self loop
    }
}

// ---------------- CSR 3: scatter sources ----------------
__global__ __launch_bounds__(CNT_THR) void scatter_kernel(
    const int* __restrict__ src, const int* __restrict__ dst,
    int* __restrict__ cursor, int* __restrict__ srcS, int E) {
    const int base = blockIdx.x * CNT_CHUNK + threadIdx.x * EPT;
    #pragma unroll
    for (int k = 0; k < EPT; ++k) {
        int e = base + k;
        if (e < E) {
            int s = src[e], d = dst[e];
            int p = atomicAdd(&cursor[d], 1);
            srcS[p] = s;
        }
    }
}

// ---------------- MFMA linear (fp32 input): Y16 = fp16((Xf@W)*dinv) ----------------
// 2 node-tiles per WG (grid 782).
// mfma_f32_16x16x32_f16: A[m=lane&15][k=(lane>>4)*8+j], C/D col=lane&15, row=quad*4+r.
template <int K>
__global__ __launch_bounds__(256) void linear_mfma_f32_kernel(
    const float* __restrict__ Xf, const float* __restrict__ W,
    const float* __restrict__ dinv, _Float16* __restrict__ Y, int n) {
    constexpr int KC = K / 32;
    __shared__ _Float16 Bf[KC * 4 * 64 * 8];  // B-fragment order; K=128 -> 16KB
    const int tid = threadIdx.x;
    for (int i = tid; i < KC * 4 * 64 * 8; i += 256) {
        int j = i & 7, lane = (i >> 3) & 63, tile = (i >> 9) & 3, kc = i >> 11;
        int k = kc * 32 + ((lane >> 4) << 3) + j;
        int col = tile * 16 + (lane & 15);
        Bf[i] = (_Float16)W[k * 64 + col];
    }
    __syncthreads();
    const int lane = tid & 63, wid = tid >> 6;
    const int mrow = lane & 15, quad = lane >> 4;
    #pragma unroll
    for (int tt = 0; tt < 2; ++tt) {
        const int base = (blockIdx.x * 2 + tt) * 64 + wid * 16;
        if (base >= n) continue;
        const int anode = min(base + mrow, n - 1);
        floatx4 acc[4] = {{0, 0, 0, 0}, {0, 0, 0, 0}, {0, 0, 0, 0}, {0, 0, 0, 0}};
        #pragma unroll
        for (int kc = 0; kc < KC; ++kc) {
            float4 xa = *(const float4*)&Xf[(size_t)anode * K + kc * 32 + quad * 8];
            float4 xb = *(const float4*)&Xf[(size_t)anode * K + kc * 32 + quad * 8 + 4];
            half8 a;
            a[0] = (_Float16)xa.x; a[1] = (_Float16)xa.y; a[2] = (_Float16)xa.z; a[3] = (_Float16)xa.w;
            a[4] = (_Float16)xb.x; a[5] = (_Float16)xb.y; a[6] = (_Float16)xb.z; a[7] = (_Float16)xb.w;
            #pragma unroll
            for (int t = 0; t < 4; ++t) {
                half8 b = *(const half8*)&Bf[((kc * 4 + t) * 64 + lane) * 8];
                acc[t] = __builtin_amdgcn_mfma_f32_16x16x32_f16(a, b, acc[t], 0, 0, 0);
            }
        }
        #pragma unroll
        for (int r = 0; r < 4; ++r) {
            int node = base + quad * 4 + r;
            if (node < n) {
                float di = dinv[node];
                #pragma unroll
                for (int t = 0; t < 4; ++t)
                    Y[(size_t)node * 64 + t * 16 + mrow] = (_Float16)(acc[t][r] * di);
            }
        }
    }
}

// ---------------- MFMA linear (fp16 input), K=64, 2 tiles per WG ----------------
__global__ __launch_bounds__(256) void linear_mfma_f16_kernel(
    const _Float16* __restrict__ Xh, const float* __restrict__ W,
    const float* __restrict__ dinv, _Float16* __restrict__ Y, int n) {
    constexpr int K = 64, KC = 2;
    __shared__ _Float16 Bf[KC * 4 * 64 * 8];  // 8KB
    const int tid = threadIdx.x;
    for (int i = tid; i < KC * 4 * 64 * 8; i += 256) {
        int j = i & 7, lane = (i >> 3) & 63, tile = (i >> 9) & 3, kc = i >> 11;
        int k = kc * 32 + ((lane >> 4) << 3) + j;
        int col = tile * 16 + (lane & 15);
        Bf[i] = (_Float16)W[k * 64 + col];
    }
    __syncthreads();
    const int lane = tid & 63, wid = tid >> 6;
    const int mrow = lane & 15, quad = lane >> 4;
    #pragma unroll
    for (int tt = 0; tt < 2; ++tt) {
        const int base = (blockIdx.x * 2 + tt) * 64 + wid * 16;
        if (base >= n) continue;
        const int anode = min(base + mrow, n - 1);
        floatx4 acc[4] = {{0, 0, 0, 0}, {0, 0, 0, 0}, {0, 0, 0, 0}, {0, 0, 0, 0}};
        #pragma unroll
        for (int kc = 0; kc < KC; ++kc) {
            half8 a = *(const half8*)&Xh[(size_t)anode * K + kc * 32 + quad * 8];
            #pragma unroll
            for (int t = 0; t < 4; ++t) {
                half8 b = *(const half8*)&Bf[((kc * 4 + t) * 64 + lane) * 8];
                acc[t] = __builtin_amdgcn_mfma_f32_16x16x32_f16(a, b, acc[t], 0, 0, 0);
            }
        }
        #pragma unroll
        for (int r = 0; r < 4; ++r) {
            int node = base + quad * 4 + r;
            if (node < n) {
                float di = dinv[node];
                #pragma unroll
                for (int t = 0; t < 4; ++t)
                    Y[(size_t)node * 64 + t * 16 + mrow] = (_Float16)(acc[t][r] * di);
            }
        }
    }
}

// ---------------- linear3: Y16[n][8] = fp16(pad8((Xh@W3)*dinv)) ----------------
__global__ __launch_bounds__(256) void linear3_kernel(const __half* __restrict__ Xh,
                                                      const float* __restrict__ W,
                                                      const float* __restrict__ dinv,
                                                      __half* __restrict__ Y, int n) {
    __shared__ float Wl[64 * 6];
    __shared__ float Xs[32][65];
    const int tid = threadIdx.x;
    for (int i = tid; i < 64 * 6; i += 256) Wl[i] = W[i];
    const int sub = tid >> 3;
    const int feat = tid & 7;
    for (int base = blockIdx.x * 32; base < n; base += gridDim.x * 32) {
        __syncthreads();
        for (int i = tid; i < 32 * 64; i += 256) {
            int r = i >> 6, c = i & 63;
            int node = base + r;
            Xs[r][c] = (node < n) ? __half2float(Xh[(size_t)node * 64 + c]) : 0.f;
        }
        __syncthreads();
        int node = base + sub;
        if (node < n) {
            float r = 0.f;
            if (feat < 6) {
                float acc = 0.f;
                #pragma unroll
                for (int k = 0; k < 64; ++k) acc = fmaf(Xs[sub][k], Wl[k * 6 + feat], acc);
                r = acc * dinv[node];
            }
            Y[(size_t)node * 8 + feat] = __float2half_rn(r);
        }
    }
}

// ---------------- aggregate 64 feats: wave/node, packed accum, unroll-4 ----------------
__global__ __launch_bounds__(256) void agg64_kernel(
    const _Float16* __restrict__ Hs, const float* __restrict__ dinv,
    const int* __restrict__ srcS, const int2* __restrict__ rows,
    const float* __restrict__ bias, _Float16* __restrict__ Out,
    int n, int do_relu) {
    const int wave = (blockIdx.x * blockDim.x + threadIdx.x) >> 6;
    const int lane = threadIdx.x & 63;
    if (wave >= n) return;
    const int slot = lane >> 3;  // edge slot 0..7
    const int f8 = lane & 7;     // feat slice [f8*8, f8*8+8)
    const int2 row = rows[wave];
    const int beg = row.x, end = row.y;
    half8 hA, hB;
    #pragma unroll
    for (int i = 0; i < 8; ++i) { hA[i] = (_Float16)0.f; hB[i] = (_Float16)0.f; }
    int j = beg;
    for (; j + 32 <= end; j += 32) {      // 32 edges: 4 gathers in flight
        int s0 = srcS[j      + slot];
        int s1 = srcS[j + 8  + slot];
        int s2 = srcS[j + 16 + slot];
        int s3 = srcS[j + 24 + slot];
        half8 v0 = *(const half8*)&Hs[(size_t)s0 * 64 + f8 * 8];
        half8 v1 = *(const half8*)&Hs[(size_t)s1 * 64 + f8 * 8];
        half8 v2 = *(const half8*)&Hs[(size_t)s2 * 64 + f8 * 8];
        half8 v3 = *(const half8*)&Hs[(size_t)s3 * 64 + f8 * 8];
        hA += v0; hB += v1; hA += v2; hB += v3;
    }
    for (; j + 16 <= end; j += 16) {      // 16 edges
        int s0 = srcS[j + slot];
        int s1 = srcS[j + 8 + slot];
        half8 v0 = *(const half8*)&Hs[(size_t)s0 * 64 + f8 * 8];
        half8 v1 = *(const half8*)&Hs[(size_t)s1 * 64 + f8 * 8];
        hA += v0; hB += v1;
    }
    for (; j < end; j += 8) {             // tail, 8 edges (exec-masked)
        int jj = j + slot;
        if (jj < end) {
            half8 v = *(const half8*)&Hs[(size_t)srcS[jj] * 64 + f8 * 8];
            hA += v;
        }
    }
    half8 ht = hA + hB;
    #pragma unroll
    for (int mask = 8; mask <= 32; mask <<= 1) {  // packed fold over slots
        int4 ci = *(int4*)&ht, oi;
        oi.x = __shfl_xor(ci.x, mask);
        oi.y = __shfl_xor(ci.y, mask);
        oi.z = __shfl_xor(ci.z, mask);
        oi.w = __shfl_xor(ci.w, mask);
        ht += *(half8*)&oi;
    }
    half8 self = *(const half8*)&Hs[(size_t)wave * 64 + f8 * 8];
    const float di = dinv[wave];
    float4 b0 = *(const float4*)&bias[f8 * 8];
    float4 b1 = *(const float4*)&bias[f8 * 8 + 4];
    float bb[8] = {b0.x, b0.y, b0.z, b0.w, b1.x, b1.y, b1.z, b1.w};
    half8 o;
    #pragma unroll
    for (int i = 0; i < 8; ++i) {
        float t = ((float)ht[i] + (float)self[i]) * di + bb[i];
        if (do_relu) t = fmaxf(t, 0.f);
        o[i] = (_Float16)t;
    }
    if (slot == 0) *(half8*)&Out[(size_t)wave * 64 + f8 * 8] = o;
}

// ---------------- aggregate 6 feats + bias + log_softmax: lane-per-edge ----------------
__global__ __launch_bounds__(256) void agg6_lsm_kernel(
    const _Float16* __restrict__ Hs6, const float* __restrict__ dinv,
    const int* __restrict__ srcS, const int2* __restrict__ rows,
    const float* __restrict__ bias, float* __restrict__ out, int n) {
    const int wave = (blockIdx.x * blockDim.x + threadIdx.x) >> 6;
    const int lane = threadIdx.x & 63;
    if (wave >= n) return;
    const int2 row = rows[wave];
    const int beg = row.x, end = row.y;
    half8 ht;
    #pragma unroll
    for (int i = 0; i < 8; ++i) ht[i] = (_Float16)0.f;
    for (int j = beg + lane; j < end; j += 64) {          // 1 iter typ. (deg~32)
        int s = srcS[j];
        ht += *(const half8*)&Hs6[(size_t)s * 8];          // 16B row gather
    }
    #pragma unroll
    for (int mask = 1; mask <= 32; mask <<= 1) {          // packed fold, 64 lanes
        int4 ci = *(int4*)&ht, oi;
        oi.x = __shfl_xor(ci.x, mask);
        oi.y = __shfl_xor(ci.y, mask);
        oi.z = __shfl_xor(ci.z, mask);
        oi.w = __shfl_xor(ci.w, mask);
        ht += *(half8*)&oi;
    }
    // all lanes now hold the full edge-sum; redundant per-lane epilogue
    half8 self = *(const half8*)&Hs6[(size_t)wave * 8];
    const float di = dinv[wave];
    float a[6];
    #pragma unroll
    for (int q = 0; q < 6; ++q)
        a[q] = ((float)ht[q] + (float)self[q]) * di + bias[q];
    float mx = a[0];
    #pragma unroll
    for (int q = 1; q < 6; ++q) mx = fmaxf(mx, a[q]);
    float sum = 0.f;
    #pragma unroll
    for (int q = 0; q < 6; ++q) sum += expf(a[q] - mx);
    float lse = mx + logf(sum);
    if (lane == 0) {
        float* op = &out[(size_t)wave * 6];               // 24B-aligned -> 8B stores
        *(float2*)(op)     = make_float2(a[0] - lse, a[1] - lse);
        *(float2*)(op + 2) = make_float2(a[2] - lse, a[3] - lse);
        *(float2*)(op + 4) = make_float2(a[4] - lse, a[5] - lse);
    }
}

// ---------------------------------------------------------------------------
extern "C" void kernel_launch(void* const* d_in, const int* in_sizes, int n_in,
                              void* d_out, int out_size, void* d_ws, size_t ws_size,
                              hipStream_t stream) {
    const float* x  = (const float*)d_in[0];
    const int*   ei = (const int*)d_in[1];
    const float* W1 = (const float*)d_in[2];
    const float* b1 = (const float*)d_in[3];
    const float* W2 = (const float*)d_in[4];
    const float* b2 = (const float*)d_in[5];
    const float* W3 = (const float*)d_in[6];
    const float* b3 = (const float*)d_in[7];
    float* out = (float*)d_out;

    const int n = in_sizes[0] / 128;  // 100000
    const int E = in_sizes[1] / 2;    // 3200000
    const int* src = ei;
    const int* dst = ei + E;

    // ---- workspace carve ----
    char* ws = (char*)d_ws;
    auto carve = [&](size_t bytes) { char* p = ws; ws += WS_ALIGN(bytes); return p; };
    int*      deg    = (int*)     carve((size_t)n * 4);
    int*      cursor = (int*)     carve((size_t)n * 4);
    float*    dinv   = (float*)   carve((size_t)n * 4);
    int2*     rows   = (int2*)    carve((size_t)n * 8);
    int*      srcS   = (int*)     carve((size_t)E * 4);             // 12.8 MB
    _Float16* hsA    = (_Float16*)carve((size_t)n * 64 * 2 + 4096); // 12.8 MB
    _Float16* hsB    = (_Float16*)carve((size_t)n * 64 * 2 + 4096); // 12.8 MB
    _Float16* hsC    = (_Float16*)carve((size_t)n * 8 * 2);         // 1.6 MB
    (void)ws_size; (void)n_in; (void)out_size;

    // ---- build CSR (direct) ----
    (void)hipMemsetAsync(deg, 0, (size_t)n * 4, stream);
    const int edgeGrid = (E + CNT_CHUNK - 1) / CNT_CHUNK;   // 782
    count_kernel<<<edgeGrid, CNT_THR, 0, stream>>>(dst, deg, E);
    rows_kernel<<<(n + 255) / 256, 256, 0, stream>>>(deg, rows, cursor, dinv, n);
    scatter_kernel<<<edgeGrid, CNT_THR, 0, stream>>>(src, dst, cursor, srcS, E);

    const int aggGrid = (n + 3) / 4;       // wave per node, 4 waves/WG
    const int linGrid = (n + 127) / 128;   // 128 nodes per WG (2 tiles)

    // ---- layer 1 ----
    linear_mfma_f32_kernel<128><<<linGrid, 256, 0, stream>>>(x, W1, dinv, hsA, n);
    agg64_kernel<<<aggGrid, 256, 0, stream>>>(hsA, dinv, srcS, rows, b1, hsB, n, 1);

    // ---- layer 2 ----
    linear_mfma_f16_kernel<<<linGrid, 256, 0, stream>>>(hsB, W2, dinv, hsA, n);
    agg64_kernel<<<aggGrid, 256, 0, stream>>>(hsA, dinv, srcS, rows, b2, hsB, n, 1);

    // ---- layer 3 ----
    linear3_kernel<<<2048, 256, 0, stream>>>((const __half*)hsB, W3, dinv, (__half*)hsC, n);
    agg6_lsm_kernel<<<aggGrid, 256, 0, stream>>>(hsC, dinv, srcS, rows, b3, out, n);
}

// Round 8
// 344.513 us; speedup vs baseline: 1.7933x; 1.7933x over previous
//
#include <hip/hip_runtime.h>
#include <hip/hip_fp16.h>
#include <math.h>

// ---------------------------------------------------------------------------
// GCN 3-layer forward, round 18.
// out[i] = dinv[i] * ( sum_{e:dst=i} Hs[src] + Hs[i] ) + b,  Hs = (X@W)*dinv.
// Round-18 delta vs round-15 (proven 356us):
//  - FAT KERNEL: bin (CSR phase 1) and lin1 run in ONE dispatch, disjoint
//    block ranges -> overlap on one stream. Enabled by moving the dinv
//    scaling out of lin1 (writes unscaled h1) into agg64-L1's gather loop
//    (pk_add -> pk_fma with dinv[src], same op count, L2-hot 4B loads).
//  - lin3 FUSED into agg64-L2 epilogue the cheap way (output feats stay
//    distributed: 48 FMA/lane vs W3-LDS + 3-level fold). Deletes linear3
//    (12.8MB R + 1.6MB W) and agg64-L2's 12.8MB output write.
//  - CSR slab build = round-15 (r17 proved direct scatter = 180us, 16x amp).
// ---------------------------------------------------------------------------

#define WS_ALIGN(x) (((x) + 255) & ~(size_t)255)
#define BKN 256                 // nodes per bin/sort bucket
#define CAP 9216                // slab capacity per bucket (mean 8184; +11 sigma)
#define EPT 8                   // edges per thread in bin kernel
#define BIN_THR 512
#define BIN_CHUNK (BIN_THR * EPT)  // 4096 edges per WG

typedef _Float16 half8 __attribute__((ext_vector_type(8)));
typedef float floatx4 __attribute__((ext_vector_type(4)));

// ---------------- fat: bin (blocks [0,binG)) || lin1 (blocks [binG,+linG)) ----------------
__global__ __launch_bounds__(512) void fat_bin_lin1_kernel(
    const int* __restrict__ src, const int* __restrict__ dst,
    int* __restrict__ cur, int* __restrict__ slab, int E, int NB, int binG,
    const float* __restrict__ Xf, const float* __restrict__ W1,
    _Float16* __restrict__ Y, int n) {
    __shared__ int smem[5632];   // bin: cnt/incl/gbase[512]x3 + stag[4096] = 22.5KB
    const int tid = threadIdx.x;
    if (blockIdx.x < binG) {
        // ---------------- bin role (round-15 LDS counting sort) ----------------
        int* cnt   = smem;
        int* incl  = smem + 512;
        int* gbase = smem + 1024;
        int* stag  = smem + 1536;
        const int base = blockIdx.x * BIN_CHUNK + tid * EPT;
        cnt[tid] = 0;
        __syncthreads();
        int b[EPT], w[EPT], lp[EPT];
        #pragma unroll
        for (int k = 0; k < EPT; ++k) {
            int e = base + k;
            if (e < E) {
                int s = src[e], d = dst[e];
                b[k] = d >> 8;
                w[k] = (s << 8) | (d & 255);
            } else b[k] = -1;
        }
        #pragma unroll
        for (int k = 0; k < EPT; ++k)
            if (b[k] >= 0) lp[k] = atomicAdd(&cnt[b[k]], 1);
        __syncthreads();
        incl[tid] = cnt[tid];
        __syncthreads();
        for (int off = 1; off < 512; off <<= 1) {
            int v = 0;
            if (tid >= off) v = incl[tid - off];
            __syncthreads();
            incl[tid] += v;
            __syncthreads();
        }
        if (tid < NB) {
            int c = cnt[tid];
            gbase[tid] = c ? atomicAdd(&cur[tid], c) : 0;
        }
        #pragma unroll
        for (int k = 0; k < EPT; ++k)
            if (b[k] >= 0) stag[incl[b[k]] - cnt[b[k]] + lp[k]] = w[k];
        __syncthreads();
        const int total = incl[NB - 1];
        for (int idx = tid; idx < total; idx += BIN_THR) {
            int wv = stag[idx];
            int lo = 0, hi = NB - 1;
            while (lo < hi) { int mid = (lo + hi) >> 1; if (incl[mid] > idx) hi = mid; else lo = mid + 1; }
            int excl = incl[lo] - cnt[lo];
            int p = gbase[lo] + (idx - excl);
            if (p < CAP) slab[(size_t)lo * CAP + p] = wv;
        }
    } else {
        // ---------------- lin1 role: Y16 = fp16(X @ W1), UNSCALED ----------------
        constexpr int K = 128, KC = 4;
        _Float16* Bf = (_Float16*)smem;   // 16KB B-fragment staging
        for (int i = tid; i < KC * 4 * 64 * 8; i += 512) {
            int j = i & 7, lane = (i >> 3) & 63, tile = (i >> 9) & 3, kc = i >> 11;
            int k = kc * 32 + ((lane >> 4) << 3) + j;
            int col = tile * 16 + (lane & 15);
            Bf[i] = (_Float16)W1[k * 64 + col];
        }
        __syncthreads();
        const int lane = tid & 63, wid = tid >> 6;   // 8 waves
        const int mrow = lane & 15, quad = lane >> 4;
        const int lblk = blockIdx.x - binG;
        #pragma unroll
        for (int tt = 0; tt < 2; ++tt) {             // 8 waves x 2 groups = 256 nodes
            const int base = lblk * 256 + wid * 32 + tt * 16;
            if (base >= n) continue;
            const int anode = min(base + mrow, n - 1);
            floatx4 acc[4] = {{0, 0, 0, 0}, {0, 0, 0, 0}, {0, 0, 0, 0}, {0, 0, 0, 0}};
            #pragma unroll
            for (int kc = 0; kc < KC; ++kc) {
                float4 xa = *(const float4*)&Xf[(size_t)anode * K + kc * 32 + quad * 8];
                float4 xb = *(const float4*)&Xf[(size_t)anode * K + kc * 32 + quad * 8 + 4];
                half8 a;
                a[0] = (_Float16)xa.x; a[1] = (_Float16)xa.y; a[2] = (_Float16)xa.z; a[3] = (_Float16)xa.w;
                a[4] = (_Float16)xb.x; a[5] = (_Float16)xb.y; a[6] = (_Float16)xb.z; a[7] = (_Float16)xb.w;
                #pragma unroll
                for (int t = 0; t < 4; ++t) {
                    half8 b = *(const half8*)&Bf[((kc * 4 + t) * 64 + lane) * 8];
                    acc[t] = __builtin_amdgcn_mfma_f32_16x16x32_f16(a, b, acc[t], 0, 0, 0);
                }
            }
            #pragma unroll
            for (int r = 0; r < 4; ++r) {
                int node = base + quad * 4 + r;
                if (node < n) {
                    #pragma unroll
                    for (int t = 0; t < 4; ++t)
                        Y[(size_t)node * 64 + t * 16 + mrow] = (_Float16)acc[t][r];
                }
            }
        }
    }
}

// ---------------- per-bucket counting sort -> per-node CSR + dinv ----------------
__global__ __launch_bounds__(512) void bucket_sort_kernel(
    const int* __restrict__ slab, const int* __restrict__ cur,
    int* __restrict__ srcS, int2* __restrict__ rows,
    float* __restrict__ dinv, int n) {
    __shared__ int cnt[BKN], s[BKN], cursor[BKN];
    const int b = blockIdx.x, tid = threadIdx.x;
    const int m = min(cur[b], CAP);
    const int* sp = slab + (size_t)b * CAP;
    if (tid < BKN) cnt[tid] = 0;
    __syncthreads();
    for (int j = tid; j < m; j += 512) atomicAdd(&cnt[sp[j] & (BKN - 1)], 1);
    __syncthreads();
    if (tid < BKN) s[tid] = cnt[tid];
    __syncthreads();
    for (int off = 1; off < BKN; off <<= 1) {
        int v = 0;
        if (tid < BKN && tid >= off) v = s[tid - off];
        __syncthreads();
        if (tid < BKN) s[tid] += v;
        __syncthreads();
    }
    if (tid < BKN) {
        int ofs = s[tid] - cnt[tid];
        cursor[tid] = ofs;
        int node = b * BKN + tid;
        if (node < n) {
            rows[node] = make_int2(b * CAP + ofs, b * CAP + ofs + cnt[tid]);
            dinv[node] = rsqrtf((float)(cnt[tid] + 1));
        }
    }
    __syncthreads();
    for (int j = tid; j < m; j += 512) {
        int w = sp[j];
        int p = atomicAdd(&cursor[w & (BKN - 1)], 1);
        srcS[(size_t)b * CAP + p] = w >> 8;
    }
}

// ---------------- MFMA linear (fp16 input), K=64, 4 tiles per WG ----------------
__global__ __launch_bounds__(256) void linear_mfma_f16_kernel(
    const _Float16* __restrict__ Xh, const float* __restrict__ W,
    const float* __restrict__ dinv, _Float16* __restrict__ Y, int n) {
    constexpr int K = 64, KC = 2;
    __shared__ _Float16 Bf[KC * 4 * 64 * 8];  // 8KB
    const int tid = threadIdx.x;
    for (int i = tid; i < KC * 4 * 64 * 8; i += 256) {
        int j = i & 7, lane = (i >> 3) & 63, tile = (i >> 9) & 3, kc = i >> 11;
        int k = kc * 32 + ((lane >> 4) << 3) + j;
        int col = tile * 16 + (lane & 15);
        Bf[i] = (_Float16)W[k * 64 + col];
    }
    __syncthreads();
    const int lane = tid & 63, wid = tid >> 6;
    const int mrow = lane & 15, quad = lane >> 4;
    #pragma unroll
    for (int tt = 0; tt < 4; ++tt) {
        const int base = (blockIdx.x * 4 + tt) * 64 + wid * 16;
        if (base >= n) continue;
        const int anode = min(base + mrow, n - 1);
        floatx4 acc[4] = {{0, 0, 0, 0}, {0, 0, 0, 0}, {0, 0, 0, 0}, {0, 0, 0, 0}};
        #pragma unroll
        for (int kc = 0; kc < KC; ++kc) {
            half8 a = *(const half8*)&Xh[(size_t)anode * K + kc * 32 + quad * 8];
            #pragma unroll
            for (int t = 0; t < 4; ++t) {
                half8 b = *(const half8*)&Bf[((kc * 4 + t) * 64 + lane) * 8];
                acc[t] = __builtin_amdgcn_mfma_f32_16x16x32_f16(a, b, acc[t], 0, 0, 0);
            }
        }
        #pragma unroll
        for (int r = 0; r < 4; ++r) {
            int node = base + quad * 4 + r;
            if (node < n) {
                float di = dinv[node];
                #pragma unroll
                for (int t = 0; t < 4; ++t)
                    Y[(size_t)node * 64 + t * 16 + mrow] = (_Float16)(acc[t][r] * di);
            }
        }
    }
}

// ---------------- agg64s (L1): gather UNSCALED h1, scale by dinv[src] in-loop ----------------
// out[i] = relu( (sum_s dinv_s*h1[s] + dinv_i*h1[i]) * dinv_i + b1 )
__global__ __launch_bounds__(256) void agg64s_kernel(
    const _Float16* __restrict__ H1, const float* __restrict__ dinv,
    const int* __restrict__ srcS, const int2* __restrict__ rows,
    const float* __restrict__ bias, _Float16* __restrict__ Out, int n) {
    const int wave = (blockIdx.x * blockDim.x + threadIdx.x) >> 6;
    const int lane = threadIdx.x & 63;
    if (wave >= n) return;
    const int slot = lane >> 3;  // edge slot 0..7
    const int f8 = lane & 7;     // feat slice [f8*8, f8*8+8)
    const int2 row = rows[wave];
    const int beg = row.x, end = row.y;
    half8 hA, hB;
    #pragma unroll
    for (int i = 0; i < 8; ++i) { hA[i] = (_Float16)0.f; hB[i] = (_Float16)0.f; }
    int j = beg;
    for (; j + 32 <= end; j += 32) {      // 32 edges: 4 gathers in flight
        int s0 = srcS[j      + slot];
        int s1 = srcS[j + 8  + slot];
        int s2 = srcS[j + 16 + slot];
        int s3 = srcS[j + 24 + slot];
        _Float16 d0 = (_Float16)dinv[s0];
        _Float16 d1 = (_Float16)dinv[s1];
        _Float16 d2 = (_Float16)dinv[s2];
        _Float16 d3 = (_Float16)dinv[s3];
        half8 v0 = *(const half8*)&H1[(size_t)s0 * 64 + f8 * 8];
        half8 v1 = *(const half8*)&H1[(size_t)s1 * 64 + f8 * 8];
        half8 v2 = *(const half8*)&H1[(size_t)s2 * 64 + f8 * 8];
        half8 v3 = *(const half8*)&H1[(size_t)s3 * 64 + f8 * 8];
        hA += v0 * d0; hB += v1 * d1; hA += v2 * d2; hB += v3 * d3;
    }
    for (; j + 16 <= end; j += 16) {      // 16 edges
        int s0 = srcS[j + slot];
        int s1 = srcS[j + 8 + slot];
        _Float16 d0 = (_Float16)dinv[s0];
        _Float16 d1 = (_Float16)dinv[s1];
        half8 v0 = *(const half8*)&H1[(size_t)s0 * 64 + f8 * 8];
        half8 v1 = *(const half8*)&H1[(size_t)s1 * 64 + f8 * 8];
        hA += v0 * d0; hB += v1 * d1;
    }
    for (; j < end; j += 8) {             // tail (exec-masked)
        int jj = j + slot;
        if (jj < end) {
            int s0 = srcS[jj];
            _Float16 d0 = (_Float16)dinv[s0];
            half8 v = *(const half8*)&H1[(size_t)s0 * 64 + f8 * 8];
            hA += v * d0;
        }
    }
    half8 ht = hA + hB;
    #pragma unroll
    for (int mask = 8; mask <= 32; mask <<= 1) {  // packed fold over slots
        int4 ci = *(int4*)&ht, oi;
        oi.x = __shfl_xor(ci.x, mask);
        oi.y = __shfl_xor(ci.y, mask);
        oi.z = __shfl_xor(ci.z, mask);
        oi.w = __shfl_xor(ci.w, mask);
        ht += *(half8*)&oi;
    }
    half8 self = *(const half8*)&H1[(size_t)wave * 64 + f8 * 8];
    const float di = dinv[wave];
    float4 b0 = *(const float4*)&bias[f8 * 8];
    float4 b1v = *(const float4*)&bias[f8 * 8 + 4];
    float bb[8] = {b0.x, b0.y, b0.z, b0.w, b1v.x, b1v.y, b1v.z, b1v.w};
    half8 o;
    #pragma unroll
    for (int i = 0; i < 8; ++i) {
        float t = ((float)ht[i] + di * (float)self[i]) * di + bb[i];
        o[i] = (_Float16)fmaxf(t, 0.f);
    }
    if (slot == 0) *(half8*)&Out[(size_t)wave * 64 + f8 * 8] = o;
}

// ---------------- agg64w3 (L2): aggregate Hs2 + relu -> h2, project W3, write hsC ----------------
// h2[f] = relu( (sum_s Hs2[s] + Hs2[i]) * di + b2[f] );  hsC[i][q] = di * sum_f h2[f] W3[f][q]
__global__ __launch_bounds__(256) void agg64w3_kernel(
    const _Float16* __restrict__ Hs, const float* __restrict__ dinv,
    const int* __restrict__ srcS, const int2* __restrict__ rows,
    const float* __restrict__ bias, const float* __restrict__ W3,
    __half* __restrict__ Yc, int n) {
    __shared__ float W3l[64 * 6];
    const int tid = threadIdx.x;
    for (int i = tid; i < 64 * 6; i += 256) W3l[i] = W3[i];
    __syncthreads();
    const int wave = (blockIdx.x * blockDim.x + tid) >> 6;
    const int lane = tid & 63;
    if (wave >= n) return;
    const int slot = lane >> 3;
    const int f8 = lane & 7;
    const int2 row = rows[wave];
    const int beg = row.x, end = row.y;
    half8 hA, hB;
    #pragma unroll
    for (int i = 0; i < 8; ++i) { hA[i] = (_Float16)0.f; hB[i] = (_Float16)0.f; }
    int j = beg;
    for (; j + 32 <= end; j += 32) {
        int s0 = srcS[j      + slot];
        int s1 = srcS[j + 8  + slot];
        int s2 = srcS[j + 16 + slot];
        int s3 = srcS[j + 24 + slot];
        half8 v0 = *(const half8*)&Hs[(size_t)s0 * 64 + f8 * 8];
        half8 v1 = *(const half8*)&Hs[(size_t)s1 * 64 + f8 * 8];
        half8 v2 = *(const half8*)&Hs[(size_t)s2 * 64 + f8 * 8];
        half8 v3 = *(const half8*)&Hs[(size_t)s3 * 64 + f8 * 8];
        hA += v0; hB += v1; hA += v2; hB += v3;
    }
    for (; j + 16 <= end; j += 16) {
        int s0 = srcS[j + slot];
        int s1 = srcS[j + 8 + slot];
        half8 v0 = *(const half8*)&Hs[(size_t)s0 * 64 + f8 * 8];
        half8 v1 = *(const half8*)&Hs[(size_t)s1 * 64 + f8 * 8];
        hA += v0; hB += v1;
    }
    for (; j < end; j += 8) {
        int jj = j + slot;
        if (jj < end) {
            half8 v = *(const half8*)&Hs[(size_t)srcS[jj] * 64 + f8 * 8];
            hA += v;
        }
    }
    half8 ht = hA + hB;
    #pragma unroll
    for (int mask = 8; mask <= 32; mask <<= 1) {
        int4 ci = *(int4*)&ht, oi;
        oi.x = __shfl_xor(ci.x, mask);
        oi.y = __shfl_xor(ci.y, mask);
        oi.z = __shfl_xor(ci.z, mask);
        oi.w = __shfl_xor(ci.w, mask);
        ht += *(half8*)&oi;
    }
    half8 self = *(const half8*)&Hs[(size_t)wave * 64 + f8 * 8];
    const float di = dinv[wave];
    float4 b0 = *(const float4*)&bias[f8 * 8];
    float4 b1v = *(const float4*)&bias[f8 * 8 + 4];
    float bb[8] = {b0.x, b0.y, b0.z, b0.w, b1v.x, b1v.y, b1v.z, b1v.w};
    // h2 for this lane's 8 feats, then W3 partial projection
    float p[6] = {0.f, 0.f, 0.f, 0.f, 0.f, 0.f};
    #pragma unroll
    for (int i = 0; i < 8; ++i) {
        float h2 = fmaxf(((float)ht[i] + (float)self[i]) * di + bb[i], 0.f);
        const float* wr = &W3l[(f8 * 8 + i) * 6];
        #pragma unroll
        for (int q = 0; q < 6; ++q) p[q] = fmaf(h2, wr[q], p[q]);
    }
    #pragma unroll
    for (int mask = 1; mask <= 4; mask <<= 1) {   // fold over f8 (bits 0..2)
        #pragma unroll
        for (int q = 0; q < 6; ++q) p[q] += __shfl_xor(p[q], mask);
    }
    if (lane == 0) {
        half8 o;
        #pragma unroll
        for (int q = 0; q < 6; ++q) o[q] = (_Float16)(p[q] * di);
        o[6] = (_Float16)0.f; o[7] = (_Float16)0.f;
        *(half8*)&Yc[(size_t)wave * 8] = o;
    }
}

// ---------------- aggregate 6 feats + bias + log_softmax: lane-per-edge ----------------
__global__ __launch_bounds__(256) void agg6_lsm_kernel(
    const _Float16* __restrict__ Hs6, const float* __restrict__ dinv,
    const int* __restrict__ srcS, const int2* __restrict__ rows,
    const float* __restrict__ bias, float* __restrict__ out, int n) {
    const int wave = (blockIdx.x * blockDim.x + threadIdx.x) >> 6;
    const int lane = threadIdx.x & 63;
    if (wave >= n) return;
    const int2 row = rows[wave];
    const int beg = row.x, end = row.y;
    half8 ht;
    #pragma unroll
    for (int i = 0; i < 8; ++i) ht[i] = (_Float16)0.f;
    for (int j = beg + lane; j < end; j += 64) {          // 1 iter typ. (deg~32)
        int s = srcS[j];
        ht += *(const half8*)&Hs6[(size_t)s * 8];          // 16B row gather
    }
    #pragma unroll
    for (int mask = 1; mask <= 32; mask <<= 1) {          // packed fold, 64 lanes
        int4 ci = *(int4*)&ht, oi;
        oi.x = __shfl_xor(ci.x, mask);
        oi.y = __shfl_xor(ci.y, mask);
        oi.z = __shfl_xor(ci.z, mask);
        oi.w = __shfl_xor(ci.w, mask);
        ht += *(half8*)&oi;
    }
    half8 self = *(const half8*)&Hs6[(size_t)wave * 8];
    const float di = dinv[wave];
    float a[6];
    #pragma unroll
    for (int q = 0; q < 6; ++q)
        a[q] = ((float)ht[q] + (float)self[q]) * di + bias[q];
    float mx = a[0];
    #pragma unroll
    for (int q = 1; q < 6; ++q) mx = fmaxf(mx, a[q]);
    float sum = 0.f;
    #pragma unroll
    for (int q = 0; q < 6; ++q) sum += expf(a[q] - mx);
    float lse = mx + logf(sum);
    if (lane == 0) {
        float* op = &out[(size_t)wave * 6];
        *(float2*)(op)     = make_float2(a[0] - lse, a[1] - lse);
        *(float2*)(op + 2) = make_float2(a[2] - lse, a[3] - lse);
        *(float2*)(op + 4) = make_float2(a[4] - lse, a[5] - lse);
    }
}

// ---------------------------------------------------------------------------
extern "C" void kernel_launch(void* const* d_in, const int* in_sizes, int n_in,
                              void* d_out, int out_size, void* d_ws, size_t ws_size,
                              hipStream_t stream) {
    const float* x  = (const float*)d_in[0];
    const int*   ei = (const int*)d_in[1];
    const float* W1 = (const float*)d_in[2];
    const float* b1 = (const float*)d_in[3];
    const float* W2 = (const float*)d_in[4];
    const float* b2 = (const float*)d_in[5];
    const float* W3 = (const float*)d_in[6];
    const float* b3 = (const float*)d_in[7];
    float* out = (float*)d_out;

    const int n = in_sizes[0] / 128;  // 100000
    const int E = in_sizes[1] / 2;    // 3200000
    const int* src = ei;
    const int* dst = ei + E;
    const int NB = (n + BKN - 1) / BKN;  // 391

    // ---- workspace carve ----
    char* ws = (char*)d_ws;
    auto carve = [&](size_t bytes) { char* p = ws; ws += WS_ALIGN(bytes); return p; };
    int*      cur  = (int*)     carve((size_t)NB * 4);
    float*    dinv = (float*)   carve((size_t)n * 4);
    int*      slab = (int*)     carve((size_t)NB * CAP * 4);   // 14.4 MB
    int*      srcS = (int*)     carve((size_t)NB * CAP * 4);   // 14.4 MB
    int2*     rows = (int2*)    carve((size_t)n * 8);
    _Float16* hsA  = (_Float16*)carve((size_t)n * 64 * 2 + 4096);   // 12.8 MB
    _Float16* hsB  = (_Float16*)carve((size_t)n * 64 * 2 + 4096);   // 12.8 MB
    _Float16* hsC  = (_Float16*)carve((size_t)n * 8 * 2);           // 1.6 MB
    (void)ws_size; (void)n_in; (void)out_size;

    const int binG = (E + BIN_CHUNK - 1) / BIN_CHUNK;   // 782
    const int linG = (n + 255) / 256;                   // 391
    const int aggGrid = (n + 3) / 4;

    // ---- CSR phase 1 || layer-1 linear (independent after dinv decoupling) ----
    (void)hipMemsetAsync(cur, 0, (size_t)NB * 4, stream);
    fat_bin_lin1_kernel<<<binG + linG, 512, 0, stream>>>(
        src, dst, cur, slab, E, NB, binG, x, W1, hsA, n);

    // ---- CSR phase 2 ----
    bucket_sort_kernel<<<NB, 512, 0, stream>>>(slab, cur, srcS, rows, dinv, n);

    // ---- layer 1 aggregation (dinv[src] applied in-loop) ----
    agg64s_kernel<<<aggGrid, 256, 0, stream>>>(hsA, dinv, srcS, rows, b1, hsB, n);

    // ---- layer 2 linear ----
    linear_mfma_f16_kernel<<<(n + 255) / 256, 256, 0, stream>>>(hsB, W2, dinv, hsA, n);

    // ---- layer 2 aggregation + fused W3 projection ----
    agg64w3_kernel<<<aggGrid, 256, 0, stream>>>(hsA, dinv, srcS, rows, b2, W3, (__half*)hsC, n);

    // ---- layer 3 aggregation + log_softmax ----
    agg6_lsm_kernel<<<aggGrid, 256, 0, stream>>>(hsC, dinv, srcS, rows, b3, out, n);
}